// Round 1
// baseline (458.738 us; speedup 1.0000x reference)
//
#include <hip/hip_runtime.h>

#define NN 20000
#define NE 640000
#define NET (NE + NN)   // 660000 edges incl. self-loops

// ---------------- CSR build ----------------
__global__ void count_deg_kernel(const int* __restrict__ ei, int* __restrict__ deg) {
    int e = blockIdx.x * 256 + threadIdx.x;
    if (e < NET) {
        int dst = (e < NE) ? ei[NE + e] : (e - NE);
        atomicAdd(&deg[dst], 1);
    }
}

__global__ void scan_kernel(int* __restrict__ deg_cursor, int* __restrict__ offs) {
    __shared__ int sdata[1024];
    __shared__ int s_carry;
    int t = threadIdx.x;
    if (t == 0) s_carry = 0;
    __syncthreads();
    for (int base = 0; base < NN; base += 1024) {
        int i = base + t;
        int v = (i < NN) ? deg_cursor[i] : 0;
        sdata[t] = v;
        __syncthreads();
        for (int o = 1; o < 1024; o <<= 1) {
            int add = (t >= o) ? sdata[t - o] : 0;
            __syncthreads();
            sdata[t] += add;
            __syncthreads();
        }
        int excl = sdata[t] - v + s_carry;
        if (i < NN) { offs[i] = excl; deg_cursor[i] = excl; }
        __syncthreads();
        if (t == 1023) s_carry += sdata[1023];
        __syncthreads();
    }
    if (t == 0) offs[NN] = s_carry;
}

__global__ void fill_csr_kernel(const int* __restrict__ ei, int* __restrict__ cursor,
                                int* __restrict__ csr_src) {
    int e = blockIdx.x * 256 + threadIdx.x;
    if (e < NET) {
        int src, dst;
        if (e < NE) { src = ei[e]; dst = ei[NE + e]; }
        else        { src = dst = e - NE; }
        int pos = atomicAdd(&cursor[dst], 1);
        csr_src[pos] = src;
    }
}

// ---------------- f32 GEMM: C[M,N] = A[M,K] @ B ----------------
// BT=false: B is K x N row-major.  BT=true: B is N x K row-major (B^T logical).
template <bool BT>
__launch_bounds__(256)
__global__ void gemm_f32(const float* __restrict__ A, const float* __restrict__ B,
                         float* __restrict__ C, int M, int N, int K) {
    __shared__ float As[16][128];
    __shared__ float Bs[16][128];
    int tid = threadIdx.x;
    int tx = tid & 15, ty = tid >> 4;
    int bm = blockIdx.x * 128;
    int bn = blockIdx.y * 128;
    float acc[8][8];
#pragma unroll
    for (int i = 0; i < 8; i++)
#pragma unroll
        for (int j = 0; j < 8; j++) acc[i][j] = 0.f;

    int ar_ = tid >> 1;         // 0..127
    int akk = (tid & 1) * 8;    // 0 or 8

    for (int k0 = 0; k0 < K; k0 += 16) {
        // A tile: 128 rows x 16 k
        int grow = bm + ar_;
        if (grow < M) {
            const float* ap = A + (size_t)grow * K + k0 + akk;
            float4 a0 = *(const float4*)ap;
            float4 a1 = *(const float4*)(ap + 4);
            As[akk + 0][ar_] = a0.x; As[akk + 1][ar_] = a0.y;
            As[akk + 2][ar_] = a0.z; As[akk + 3][ar_] = a0.w;
            As[akk + 4][ar_] = a1.x; As[akk + 5][ar_] = a1.y;
            As[akk + 6][ar_] = a1.z; As[akk + 7][ar_] = a1.w;
        } else {
#pragma unroll
            for (int q = 0; q < 8; q++) As[akk + q][ar_] = 0.f;
        }
        // B tile: 16 k x 128 n
        if (!BT) {
            int bk = tid >> 4;           // 0..15
            int bnn = (tid & 15) * 8;    // 0..120
            const float* bp = B + (size_t)(k0 + bk) * N + bn + bnn;
            *(float4*)&Bs[bk][bnn]     = *(const float4*)bp;
            *(float4*)&Bs[bk][bnn + 4] = *(const float4*)(bp + 4);
        } else {
            int bn_ = tid >> 1;          // 0..127
            int bkk = (tid & 1) * 8;
            const float* bp = B + (size_t)(bn + bn_) * K + k0 + bkk;
            float4 b0 = *(const float4*)bp;
            float4 b1 = *(const float4*)(bp + 4);
            Bs[bkk + 0][bn_] = b0.x; Bs[bkk + 1][bn_] = b0.y;
            Bs[bkk + 2][bn_] = b0.z; Bs[bkk + 3][bn_] = b0.w;
            Bs[bkk + 4][bn_] = b1.x; Bs[bkk + 5][bn_] = b1.y;
            Bs[bkk + 6][bn_] = b1.z; Bs[bkk + 7][bn_] = b1.w;
        }
        __syncthreads();
#pragma unroll
        for (int k = 0; k < 16; k++) {
            float a[8], b[8];
            *(float4*)&a[0] = *(const float4*)&As[k][ty * 8];
            *(float4*)&a[4] = *(const float4*)&As[k][ty * 8 + 4];
            *(float4*)&b[0] = *(const float4*)&Bs[k][tx * 8];
            *(float4*)&b[4] = *(const float4*)&Bs[k][tx * 8 + 4];
#pragma unroll
            for (int i = 0; i < 8; i++)
#pragma unroll
                for (int j = 0; j < 8; j++) acc[i][j] += a[i] * b[j];
        }
        __syncthreads();
    }
#pragma unroll
    for (int i = 0; i < 8; i++) {
        int row = bm + ty * 8 + i;
        if (row < M) {
            float* cp = C + (size_t)row * N + bn + tx * 8;
            float4 c0 = make_float4(acc[i][0], acc[i][1], acc[i][2], acc[i][3]);
            float4 c1 = make_float4(acc[i][4], acc[i][5], acc[i][6], acc[i][7]);
            *(float4*)cp = c0;
            *(float4*)(cp + 4) = c1;
        }
    }
}

// ---------------- per-node attention coefficients al/ar ----------------
template <int CH, int HEADS>
__launch_bounds__(CH* HEADS)
__global__ void alar_kernel(const float* __restrict__ xl, const float* __restrict__ a_src,
                            const float* __restrict__ a_dst, float* __restrict__ al,
                            float* __restrict__ ar) {
    constexpr int NT = CH * HEADS;
    int n = blockIdx.x, t = threadIdx.x;
    float v = xl[(size_t)n * NT + t];
    float ps = v * a_src[t];
    float pd = v * a_dst[t];
    __shared__ float s1[NT], s2[NT];
    s1[t] = ps; s2[t] = pd;
    __syncthreads();
    int c = t & (CH - 1);
    for (int o = CH / 2; o > 0; o >>= 1) {
        if (c < o) { s1[t] += s1[t + o]; s2[t] += s2[t + o]; }
        __syncthreads();
    }
    if (c == 0) {
        int h = t / CH;
        al[n * HEADS + h] = s1[t];
        ar[n * HEADS + h] = s2[t];
    }
}

// ---------------- GAT softmax + aggregation (+bias +ELU) ----------------
template <int CH, int HEADS>
__launch_bounds__(CH* HEADS)
__global__ void gat_agg(const float* __restrict__ xl, const float* __restrict__ al,
                        const float* __restrict__ ar, const int* __restrict__ offs,
                        const int* __restrict__ csr, const float* __restrict__ bias,
                        float* __restrict__ out) {
    constexpr int NT = CH * HEADS;
    constexpr int CHUNK = 128;
    int n = blockIdx.x;
    int t = threadIdx.x;
    int e0 = offs[n], e1 = offs[n + 1];
    __shared__ float sred[NT];
    __shared__ float s_m[HEADS], s_s[HEADS];
    __shared__ int s_src[CHUNK];
    __shared__ float s_w[CHUNK * HEADS];

    float arv[HEADS];
#pragma unroll
    for (int h = 0; h < HEADS; h++) arv[h] = ar[n * HEADS + h];

    // pass 1: per-head max of leaky_relu(al[src]+ar[dst])
    float lm[HEADS];
#pragma unroll
    for (int h = 0; h < HEADS; h++) lm[h] = -1e30f;
    for (int e = e0 + t; e < e1; e += NT) {
        int s = csr[e];
#pragma unroll
        for (int h = 0; h < HEADS; h++) {
            float lg = al[s * HEADS + h] + arv[h];
            lg = lg > 0.f ? lg : 0.2f * lg;
            lm[h] = fmaxf(lm[h], lg);
        }
    }
#pragma unroll
    for (int h = 0; h < HEADS; h++) {
        sred[t] = lm[h];
        __syncthreads();
        for (int o = NT / 2; o > 0; o >>= 1) {
            if (t < o) sred[t] = fmaxf(sred[t], sred[t + o]);
            __syncthreads();
        }
        if (t == 0) s_m[h] = sred[0];
        __syncthreads();
    }
    // pass 2: per-head sum of exp
    float lsum[HEADS];
#pragma unroll
    for (int h = 0; h < HEADS; h++) lsum[h] = 0.f;
    for (int e = e0 + t; e < e1; e += NT) {
        int s = csr[e];
#pragma unroll
        for (int h = 0; h < HEADS; h++) {
            float lg = al[s * HEADS + h] + arv[h];
            lg = lg > 0.f ? lg : 0.2f * lg;
            lsum[h] += expf(lg - s_m[h]);
        }
    }
#pragma unroll
    for (int h = 0; h < HEADS; h++) {
        sred[t] = lsum[h];
        __syncthreads();
        for (int o = NT / 2; o > 0; o >>= 1) {
            if (t < o) sred[t] += sred[t + o];
            __syncthreads();
        }
        if (t == 0) s_s[h] = sred[0];
        __syncthreads();
    }
    // pass 3: weighted gather
    float acc = 0.f;
    int h = t / CH;
    for (int base = e0; base < e1; base += CHUNK) {
        int cnt = min(CHUNK, e1 - base);
        if (t < cnt) {
            int s = csr[base + t];
            s_src[t] = s;
#pragma unroll
            for (int hh = 0; hh < HEADS; hh++) {
                float lg = al[s * HEADS + hh] + arv[hh];
                lg = lg > 0.f ? lg : 0.2f * lg;
                s_w[t * HEADS + hh] = expf(lg - s_m[hh]) / s_s[hh];
            }
        }
        __syncthreads();
        for (int k = 0; k < cnt; k++) {
            acc += s_w[k * HEADS + h] * xl[(size_t)s_src[k] * NT + t];
        }
        __syncthreads();
    }
    float o = acc + bias[t];
    out[(size_t)n * NT + t] = o > 0.f ? o : (expf(o) - 1.0f);
}

// ---------------- GRU (h0=0) + heads + SIR physics ----------------
__launch_bounds__(128)
__global__ void gru_heads_kernel(const float* __restrict__ gi, const float* __restrict__ b_ih,
                                 const float* __restrict__ b_hh, const float* __restrict__ cI,
                                 const float* __restrict__ cR, const float* __restrict__ Npop,
                                 const float* __restrict__ I0, const float* __restrict__ R0,
                                 const float* __restrict__ W_I, const float* __restrict__ b_I,
                                 const float* __restrict__ W_R, const float* __restrict__ b_R,
                                 const float* __restrict__ W_sir, const float* __restrict__ b_sir,
                                 float* __restrict__ out_predI, float* __restrict__ out_predR,
                                 float* __restrict__ out_phyI, float* __restrict__ out_phyR,
                                 float* __restrict__ out_h) {
    int n = blockIdx.x, t = threadIdx.x;
    __shared__ float hc[130];
    __shared__ float s_pr[2];
    const float* g = gi + (size_t)n * 384;
    float ir = g[t] + b_ih[t];
    float iz = g[128 + t] + b_ih[128 + t];
    float ih = g[256 + t] + b_ih[256 + t];
    float r = 1.f / (1.f + expf(-(ir + b_hh[t])));
    float z = 1.f / (1.f + expf(-(iz + b_hh[128 + t])));
    float nn = tanhf(ih + r * b_hh[256 + t]);
    float hv = (1.f - z) * nn;   // + z*h_prev, h_prev = 0
    out_h[(size_t)n * 128 + t] = hv;
    hc[t] = hv;
    if (t == 0) { hc[128] = cI[n]; hc[129] = cR[n]; }
    __syncthreads();
    if (t < 32) {
        const float* Wr;
        float bb;
        int p;
        if (t < 15)      { p = t;      Wr = W_I + p * 130;   bb = b_I[p]; }
        else if (t < 30) { p = t - 15; Wr = W_R + p * 130;   bb = b_R[p]; }
        else             { p = t - 30; Wr = W_sir + p * 130; bb = b_sir[p]; }
        float s = bb;
        for (int d = 0; d < 130; d++) s += hc[d] * Wr[d];
        if (t < 15)      out_predI[(size_t)n * 15 + p] = s;
        else if (t < 30) out_predR[(size_t)n * 15 + p] = s;
        else             s_pr[p] = s;
    }
    __syncthreads();
    if (t == 0) {
        float alpha = 1.f / (1.f + expf(-s_pr[0]));
        float beta  = 1.f / (1.f + expf(-s_pr[1]));
        float Nv = Npop[n];
        float Iv = I0[n], Rv = R0[n];
        float S = Nv - Iv - Rv;
        float SoN = S / Nv;
        for (int st = 0; st < 15; st++) {
            float dIv = alpha * Iv * SoN - beta * Iv;
            float dRv = beta * Iv;
            out_phyI[(size_t)n * 15 + st] = dIv;
            out_phyR[(size_t)n * 15 + st] = dRv;
            Iv += dIv; Rv += dRv;
        }
    }
}

extern "C" void kernel_launch(void* const* d_in, const int* in_sizes, int n_in,
                              void* d_out, int out_size, void* d_ws, size_t ws_size,
                              hipStream_t stream) {
    const float* dynamic = (const float*)d_in[0];
    const int*   ei      = (const int*)d_in[1];
    const float* cI      = (const float*)d_in[2];
    const float* cR      = (const float*)d_in[3];
    const float* Npop    = (const float*)d_in[4];
    const float* I0      = (const float*)d_in[5];
    const float* R0      = (const float*)d_in[6];
    // d_in[7], d_in[8] (dI, dR) unused by reference
    const float* W1      = (const float*)d_in[9];
    const float* a_src1  = (const float*)d_in[10];
    const float* a_dst1  = (const float*)d_in[11];
    const float* b1      = (const float*)d_in[12];
    const float* W2      = (const float*)d_in[13];
    const float* a_src2  = (const float*)d_in[14];
    const float* a_dst2  = (const float*)d_in[15];
    const float* b2      = (const float*)d_in[16];
    const float* W_ih    = (const float*)d_in[17];
    // d_in[18] W_hh unused (h0 = 0)
    const float* b_ih    = (const float*)d_in[19];
    const float* b_hh    = (const float*)d_in[20];
    const float* W_I     = (const float*)d_in[21];
    const float* b_I     = (const float*)d_in[22];
    const float* W_R     = (const float*)d_in[23];
    const float* b_R     = (const float*)d_in[24];
    const float* W_sir   = (const float*)d_in[25];
    const float* b_sir   = (const float*)d_in[26];
    float* out = (float*)d_out;

    // workspace layout (~65 MB)
    int* wsi = (int*)d_ws;
    int* offs    = wsi;              // 20001 (padded 20096)
    int* cursor  = wsi + 20096;      // 20000 (padded 20096), doubles as degree array
    int* csr_src = wsi + 40192;      // 660000 (padded 660096)
    float* fp = (float*)(wsi + 700288);
    float* al1  = fp; fp += 80128;   // 20000*4
    float* ar1  = fp; fp += 80128;
    float* al2  = fp; fp += 20096;   // 20000
    float* ar2  = fp; fp += 20096;
    float* bufA = fp; fp += 5120000; // 20000*256
    float* bufB = fp; fp += 5120000; // 20000*256
    float* bufC = fp; fp += 2560000; // 20000*128
    float* bufD = fp; fp += 2560000; // 20000*128
    float* xl1 = bufA;
    float* x1  = bufB;
    float* xl2 = bufC;
    float* x2  = bufD;
    float* gi  = bufA;  // 20000*384 spans bufA+bufB (both dead by then)

    // CSR build
    hipMemsetAsync(cursor, 0, NN * sizeof(int), stream);
    count_deg_kernel<<<(NET + 255) / 256, 256, 0, stream>>>(ei, cursor);
    scan_kernel<<<1, 1024, 0, stream>>>(cursor, offs);
    fill_csr_kernel<<<(NET + 255) / 256, 256, 0, stream>>>(ei, cursor, csr_src);

    // GAT layer 1 (4 heads x 64)
    gemm_f32<false><<<dim3(157, 2), 256, 0, stream>>>(dynamic, W1, xl1, NN, 256, 128);
    alar_kernel<64, 4><<<NN, 256, 0, stream>>>(xl1, a_src1, a_dst1, al1, ar1);
    gat_agg<64, 4><<<NN, 256, 0, stream>>>(xl1, al1, ar1, offs, csr_src, b1, x1);

    // GAT layer 2 (1 head x 128)
    gemm_f32<false><<<dim3(157, 1), 256, 0, stream>>>(x1, W2, xl2, NN, 128, 256);
    alar_kernel<128, 1><<<NN, 128, 0, stream>>>(xl2, a_src2, a_dst2, al2, ar2);
    gat_agg<128, 1><<<NN, 128, 0, stream>>>(xl2, al2, ar2, offs, csr_src, b2, x2);

    // GRU input gates: gi = x2 @ W_ih^T
    gemm_f32<true><<<dim3(157, 3), 256, 0, stream>>>(x2, W_ih, gi, NN, 384, 128);

    // GRU + prediction heads + SIR recurrence
    gru_heads_kernel<<<NN, 128, 0, stream>>>(gi, b_ih, b_hh, cI, cR, Npop, I0, R0,
                                             W_I, b_I, W_R, b_R, W_sir, b_sir,
                                             out, out + 300000, out + 600000,
                                             out + 900000, out + 1200000);
}

// Round 2
// 383.008 us; speedup vs baseline: 1.1977x; 1.1977x over previous
//
#include <hip/hip_runtime.h>

#define NN 20000
#define NE 640000
#define NET (NE + NN)   // 660000 edges incl. self-loops

// ---------------- CSR build ----------------
__global__ void count_deg_kernel(const int* __restrict__ ei, int* __restrict__ deg) {
    int e = blockIdx.x * 256 + threadIdx.x;
    if (e < NET) {
        int dst = (e < NE) ? ei[NE + e] : (e - NE);
        atomicAdd(&deg[dst], 1);
    }
}

__global__ void scan_kernel(int* __restrict__ deg_cursor, int* __restrict__ offs) {
    __shared__ int sdata[1024];
    __shared__ int s_carry;
    int t = threadIdx.x;
    if (t == 0) s_carry = 0;
    __syncthreads();
    for (int base = 0; base < NN; base += 1024) {
        int i = base + t;
        int v = (i < NN) ? deg_cursor[i] : 0;
        sdata[t] = v;
        __syncthreads();
        for (int o = 1; o < 1024; o <<= 1) {
            int add = (t >= o) ? sdata[t - o] : 0;
            __syncthreads();
            sdata[t] += add;
            __syncthreads();
        }
        int excl = sdata[t] - v + s_carry;
        if (i < NN) { offs[i] = excl; deg_cursor[i] = excl; }
        __syncthreads();
        if (t == 1023) s_carry += sdata[1023];
        __syncthreads();
    }
    if (t == 0) offs[NN] = s_carry;
}

__global__ void fill_csr_kernel(const int* __restrict__ ei, int* __restrict__ cursor,
                                int* __restrict__ csr_src) {
    int e = blockIdx.x * 256 + threadIdx.x;
    if (e < NET) {
        int src, dst;
        if (e < NE) { src = ei[e]; dst = ei[NE + e]; }
        else        { src = dst = e - NE; }
        int pos = atomicAdd(&cursor[dst], 1);
        csr_src[pos] = src;
    }
}

// ---------------- fold attention vectors into input space ----------------
// w1f[k][h]   = sum_c W1[k, h*64+c] * a_src1[h,c]   (h = 0..3)
// w1f[k][4+h] = sum_c W1[k, h*64+c] * a_dst1[h,c]
__global__ void fold_w1(const float* __restrict__ W1, const float* __restrict__ a_src,
                        const float* __restrict__ a_dst, float* __restrict__ wf) {
    int k = threadIdx.x;  // 128
#pragma unroll
    for (int h = 0; h < 4; h++) {
        float s1 = 0.f, s2 = 0.f;
        for (int c = 0; c < 64; c++) {
            float w = W1[k * 256 + h * 64 + c];
            s1 += w * a_src[h * 64 + c];
            s2 += w * a_dst[h * 64 + c];
        }
        wf[k * 8 + h] = s1;
        wf[k * 8 + 4 + h] = s2;
    }
}

// w2f[k][0] = sum_c W2[k,c]*a_src2[c]; w2f[k][1] = sum_c W2[k,c]*a_dst2[c]
__global__ void fold_w2(const float* __restrict__ W2, const float* __restrict__ a_src,
                        const float* __restrict__ a_dst, float* __restrict__ wf) {
    int k = threadIdx.x;  // 256
    float s1 = 0.f, s2 = 0.f;
    for (int c = 0; c < 128; c++) {
        float w = W2[k * 128 + c];
        s1 += w * a_src[c];
        s2 += w * a_dst[c];
    }
    wf[k * 2] = s1;
    wf[k * 2 + 1] = s2;
}

// ---------------- al/ar = X @ wf  (wave per node) ----------------
template <int K, int NOUT>
__launch_bounds__(256)
__global__ void alar_apply(const float* __restrict__ X, const float* __restrict__ wf,
                           float* __restrict__ al, float* __restrict__ ar) {
    __shared__ float ws[NOUT][K];
    int t = threadIdx.x;
    for (int i = t; i < K * NOUT; i += 256) ws[i % NOUT][i / NOUT] = wf[i];
    __syncthreads();
    int wv = t >> 6, ln = t & 63;
    int n = blockIdx.x * 4 + wv;
    float p[NOUT];
#pragma unroll
    for (int o = 0; o < NOUT; o++) p[o] = 0.f;
    for (int c = ln; c < K; c += 64) {
        float x = X[(size_t)n * K + c];
#pragma unroll
        for (int o = 0; o < NOUT; o++) p[o] += x * ws[o][c];
    }
#pragma unroll
    for (int off = 32; off > 0; off >>= 1)
#pragma unroll
        for (int o = 0; o < NOUT; o++) p[o] += __shfl_xor(p[o], off, 64);
    if (ln == 0) {
        constexpr int H = NOUT / 2;
#pragma unroll
        for (int h = 0; h < H; h++) {
            al[n * H + h] = p[h];
            ar[n * H + h] = p[H + h];
        }
    }
}

// ---------------- GAT gather: out[n] = sum_e softmax-weighted X[src_e] ----------------
// HEADS weight sets share the gathered 128-wide row. FUSE: +bias +ELU epilogue.
template <int HEADS, bool FUSE>
__launch_bounds__(128)
__global__ void gat_gather(const float* __restrict__ X, const float* __restrict__ al,
                           const float* __restrict__ ar, const int* __restrict__ offs,
                           const int* __restrict__ csr, const float* __restrict__ bias,
                           float* __restrict__ out) {
    constexpr int CHUNK = 256;
    int n = blockIdx.x, t = threadIdx.x;
    int wv = t >> 6, ln = t & 63;
    int e0 = offs[n], e1 = offs[n + 1];
    __shared__ int s_src[CHUNK];
    __shared__ float s_w[CHUNK][HEADS];
    __shared__ float s_red[2][HEADS];

    float arv[HEADS], m[HEADS], srun[HEADS], accA[HEADS], accB[HEADS];
#pragma unroll
    for (int h = 0; h < HEADS; h++) {
        arv[h] = ar[n * HEADS + h];
        m[h] = -1e30f; srun[h] = 0.f; accA[h] = 0.f; accB[h] = 0.f;
    }

    for (int base = e0; base < e1; base += CHUNK) {
        int cnt = min(CHUNK, e1 - base);
        // logits -> LDS, local max
        float lmx[HEADS];
#pragma unroll
        for (int h = 0; h < HEADS; h++) lmx[h] = -1e30f;
        for (int idx = t; idx < cnt; idx += 128) {
            int s = csr[base + idx];
            s_src[idx] = s;
#pragma unroll
            for (int h = 0; h < HEADS; h++) {
                float lg = al[s * HEADS + h] + arv[h];
                lg = lg > 0.f ? lg : 0.2f * lg;
                s_w[idx][h] = lg;
                lmx[h] = fmaxf(lmx[h], lg);
            }
        }
#pragma unroll
        for (int off = 32; off > 0; off >>= 1)
#pragma unroll
            for (int h = 0; h < HEADS; h++) lmx[h] = fmaxf(lmx[h], __shfl_xor(lmx[h], off, 64));
        if (ln == 0)
#pragma unroll
            for (int h = 0; h < HEADS; h++) s_red[wv][h] = lmx[h];
        __syncthreads();  // A: s_src/s_w logits + s_red maxes visible
        float mn[HEADS];
#pragma unroll
        for (int h = 0; h < HEADS; h++) mn[h] = fmaxf(fmaxf(s_red[0][h], s_red[1][h]), m[h]);
        // rescale running state
#pragma unroll
        for (int h = 0; h < HEADS; h++) {
            float sc = expf(m[h] - mn[h]);  // 0 on first chunk
            accA[h] *= sc; accB[h] *= sc; srun[h] *= sc; m[h] = mn[h];
        }
        // weights (rewrite own s_w slots) + local sum
        float ls[HEADS];
#pragma unroll
        for (int h = 0; h < HEADS; h++) ls[h] = 0.f;
        for (int idx = t; idx < cnt; idx += 128) {
#pragma unroll
            for (int h = 0; h < HEADS; h++) {
                float w = expf(s_w[idx][h] - m[h]);
                s_w[idx][h] = w;
                ls[h] += w;
            }
        }
#pragma unroll
        for (int off = 32; off > 0; off >>= 1)
#pragma unroll
            for (int h = 0; h < HEADS; h++) ls[h] += __shfl_xor(ls[h], off, 64);
        __syncthreads();  // B: everyone done reading s_red maxes, weights written
        if (ln == 0)
#pragma unroll
            for (int h = 0; h < HEADS; h++) s_red[wv][h] = ls[h];
        __syncthreads();  // C: sums visible
#pragma unroll
        for (int h = 0; h < HEADS; h++) srun[h] += s_red[0][h] + s_red[1][h];
        // gather: 4 independent loads in flight, split acc chains
        int k = 0;
        for (; k + 4 <= cnt; k += 4) {
            const float* p0 = X + ((size_t)s_src[k + 0] << 7) + t;
            const float* p1 = X + ((size_t)s_src[k + 1] << 7) + t;
            const float* p2 = X + ((size_t)s_src[k + 2] << 7) + t;
            const float* p3 = X + ((size_t)s_src[k + 3] << 7) + t;
            float x0 = *p0, x1 = *p1, x2 = *p2, x3 = *p3;
#pragma unroll
            for (int h = 0; h < HEADS; h++) {
                accA[h] = fmaf(s_w[k + 0][h], x0, accA[h]);
                accB[h] = fmaf(s_w[k + 1][h], x1, accB[h]);
                accA[h] = fmaf(s_w[k + 2][h], x2, accA[h]);
                accB[h] = fmaf(s_w[k + 3][h], x3, accB[h]);
            }
        }
        for (; k < cnt; k++) {
            float x0 = X[((size_t)s_src[k] << 7) + t];
#pragma unroll
            for (int h = 0; h < HEADS; h++) accA[h] = fmaf(s_w[k][h], x0, accA[h]);
        }
        __syncthreads();  // D: before next chunk overwrites s_src/s_w
    }
    if (FUSE) {
        float o = (accA[0] + accB[0]) / srun[0] + bias[t];
        out[(size_t)n * 128 + t] = o > 0.f ? o : (expf(o) - 1.f);
    } else {
#pragma unroll
        for (int h = 0; h < HEADS; h++)
            out[(size_t)n * (HEADS * 128) + h * 128 + t] = (accA[h] + accB[h]) / srun[h];
    }
}

// ---------------- per-head GEMM + bias + ELU: x1[n, h*64+c] ----------------
// A = agg1 [20000][512] (head h slice at h*128), B = W1 [128][256] (cols h*64..),
// C = x1 [20000][256]
__launch_bounds__(256)
__global__ void head_gemm_elu(const float* __restrict__ A, const float* __restrict__ B,
                              const float* __restrict__ bias, float* __restrict__ C) {
    int h = blockIdx.y;
    int bm = blockIdx.x * 64;
    __shared__ float As[32][64];
    __shared__ float Bs[32][64];
    int t = threadIdx.x;
    int tx = t & 15, ty = t >> 4;
    float acc[4][4];
#pragma unroll
    for (int i = 0; i < 4; i++)
#pragma unroll
        for (int j = 0; j < 4; j++) acc[i][j] = 0.f;
    for (int k0 = 0; k0 < 128; k0 += 32) {
        {
            int r = t >> 2, kk = (t & 3) * 8;
            int gm = bm + r;
            float4 a0, a1;
            if (gm < NN) {
                const float* ap = A + (size_t)gm * 512 + h * 128 + k0 + kk;
                a0 = *(const float4*)ap; a1 = *(const float4*)(ap + 4);
            } else {
                a0 = make_float4(0.f, 0.f, 0.f, 0.f); a1 = a0;
            }
            As[kk + 0][r] = a0.x; As[kk + 1][r] = a0.y; As[kk + 2][r] = a0.z; As[kk + 3][r] = a0.w;
            As[kk + 4][r] = a1.x; As[kk + 5][r] = a1.y; As[kk + 6][r] = a1.z; As[kk + 7][r] = a1.w;
        }
        {
            int k = t >> 3, cc = (t & 7) * 8;
            const float* bp = B + (size_t)(k0 + k) * 256 + h * 64 + cc;
            *(float4*)&Bs[k][cc] = *(const float4*)bp;
            *(float4*)&Bs[k][cc + 4] = *(const float4*)(bp + 4);
        }
        __syncthreads();
#pragma unroll
        for (int k = 0; k < 32; k++) {
            float a[4], b[4];
            *(float4*)a = *(const float4*)&As[k][ty * 4];
            *(float4*)b = *(const float4*)&Bs[k][tx * 4];
#pragma unroll
            for (int i = 0; i < 4; i++)
#pragma unroll
                for (int j = 0; j < 4; j++) acc[i][j] += a[i] * b[j];
        }
        __syncthreads();
    }
#pragma unroll
    for (int i = 0; i < 4; i++) {
        int row = bm + ty * 4 + i;
        if (row < NN) {
            float4 v;
            float b0 = bias[h * 64 + tx * 4 + 0], b1 = bias[h * 64 + tx * 4 + 1];
            float b2 = bias[h * 64 + tx * 4 + 2], b3 = bias[h * 64 + tx * 4 + 3];
            float o0 = acc[i][0] + b0, o1 = acc[i][1] + b1;
            float o2 = acc[i][2] + b2, o3 = acc[i][3] + b3;
            v.x = o0 > 0.f ? o0 : expf(o0) - 1.f;
            v.y = o1 > 0.f ? o1 : expf(o1) - 1.f;
            v.z = o2 > 0.f ? o2 : expf(o2) - 1.f;
            v.w = o3 > 0.f ? o3 : expf(o3) - 1.f;
            *(float4*)&C[(size_t)row * 256 + h * 64 + tx * 4] = v;
        }
    }
}

// ---------------- f32 GEMM: C[M,N] = A[M,K] @ B ----------------
template <bool BT>
__launch_bounds__(256)
__global__ void gemm_f32(const float* __restrict__ A, const float* __restrict__ B,
                         float* __restrict__ C, int M, int N, int K) {
    __shared__ float As[16][128];
    __shared__ float Bs[16][128];
    int tid = threadIdx.x;
    int tx = tid & 15, ty = tid >> 4;
    int bm = blockIdx.x * 128;
    int bn = blockIdx.y * 128;
    float acc[8][8];
#pragma unroll
    for (int i = 0; i < 8; i++)
#pragma unroll
        for (int j = 0; j < 8; j++) acc[i][j] = 0.f;

    int ar_ = tid >> 1;
    int akk = (tid & 1) * 8;

    for (int k0 = 0; k0 < K; k0 += 16) {
        int grow = bm + ar_;
        if (grow < M) {
            const float* ap = A + (size_t)grow * K + k0 + akk;
            float4 a0 = *(const float4*)ap;
            float4 a1 = *(const float4*)(ap + 4);
            As[akk + 0][ar_] = a0.x; As[akk + 1][ar_] = a0.y;
            As[akk + 2][ar_] = a0.z; As[akk + 3][ar_] = a0.w;
            As[akk + 4][ar_] = a1.x; As[akk + 5][ar_] = a1.y;
            As[akk + 6][ar_] = a1.z; As[akk + 7][ar_] = a1.w;
        } else {
#pragma unroll
            for (int q = 0; q < 8; q++) As[akk + q][ar_] = 0.f;
        }
        if (!BT) {
            int bk = tid >> 4;
            int bnn = (tid & 15) * 8;
            const float* bp = B + (size_t)(k0 + bk) * N + bn + bnn;
            *(float4*)&Bs[bk][bnn]     = *(const float4*)bp;
            *(float4*)&Bs[bk][bnn + 4] = *(const float4*)(bp + 4);
        } else {
            int bn_ = tid >> 1;
            int bkk = (tid & 1) * 8;
            const float* bp = B + (size_t)(bn + bn_) * K + k0 + bkk;
            float4 b0 = *(const float4*)bp;
            float4 b1 = *(const float4*)(bp + 4);
            Bs[bkk + 0][bn_] = b0.x; Bs[bkk + 1][bn_] = b0.y;
            Bs[bkk + 2][bn_] = b0.z; Bs[bkk + 3][bn_] = b0.w;
            Bs[bkk + 4][bn_] = b1.x; Bs[bkk + 5][bn_] = b1.y;
            Bs[bkk + 6][bn_] = b1.z; Bs[bkk + 7][bn_] = b1.w;
        }
        __syncthreads();
#pragma unroll
        for (int k = 0; k < 16; k++) {
            float a[8], b[8];
            *(float4*)&a[0] = *(const float4*)&As[k][ty * 8];
            *(float4*)&a[4] = *(const float4*)&As[k][ty * 8 + 4];
            *(float4*)&b[0] = *(const float4*)&Bs[k][tx * 8];
            *(float4*)&b[4] = *(const float4*)&Bs[k][tx * 8 + 4];
#pragma unroll
            for (int i = 0; i < 8; i++)
#pragma unroll
                for (int j = 0; j < 8; j++) acc[i][j] += a[i] * b[j];
        }
        __syncthreads();
    }
#pragma unroll
    for (int i = 0; i < 8; i++) {
        int row = bm + ty * 8 + i;
        if (row < M) {
            float* cp = C + (size_t)row * N + bn + tx * 8;
            float4 c0 = make_float4(acc[i][0], acc[i][1], acc[i][2], acc[i][3]);
            float4 c1 = make_float4(acc[i][4], acc[i][5], acc[i][6], acc[i][7]);
            *(float4*)cp = c0;
            *(float4*)(cp + 4) = c1;
        }
    }
}

// ---------------- GRU (h0=0) + heads + SIR physics ----------------
__launch_bounds__(128)
__global__ void gru_heads_kernel(const float* __restrict__ gi, const float* __restrict__ b_ih,
                                 const float* __restrict__ b_hh, const float* __restrict__ cI,
                                 const float* __restrict__ cR, const float* __restrict__ Npop,
                                 const float* __restrict__ I0, const float* __restrict__ R0,
                                 const float* __restrict__ W_I, const float* __restrict__ b_I,
                                 const float* __restrict__ W_R, const float* __restrict__ b_R,
                                 const float* __restrict__ W_sir, const float* __restrict__ b_sir,
                                 float* __restrict__ out_predI, float* __restrict__ out_predR,
                                 float* __restrict__ out_phyI, float* __restrict__ out_phyR,
                                 float* __restrict__ out_h) {
    int n = blockIdx.x, t = threadIdx.x;
    __shared__ float hc[130];
    __shared__ float s_pr[2];
    const float* g = gi + (size_t)n * 384;
    float ir = g[t] + b_ih[t];
    float iz = g[128 + t] + b_ih[128 + t];
    float ih = g[256 + t] + b_ih[256 + t];
    float r = 1.f / (1.f + expf(-(ir + b_hh[t])));
    float z = 1.f / (1.f + expf(-(iz + b_hh[128 + t])));
    float nn = tanhf(ih + r * b_hh[256 + t]);
    float hv = (1.f - z) * nn;
    out_h[(size_t)n * 128 + t] = hv;
    hc[t] = hv;
    if (t == 0) { hc[128] = cI[n]; hc[129] = cR[n]; }
    __syncthreads();
    if (t < 32) {
        const float* Wr;
        float bb;
        int p;
        if (t < 15)      { p = t;      Wr = W_I + p * 130;   bb = b_I[p]; }
        else if (t < 30) { p = t - 15; Wr = W_R + p * 130;   bb = b_R[p]; }
        else             { p = t - 30; Wr = W_sir + p * 130; bb = b_sir[p]; }
        float s = bb;
        for (int d = 0; d < 130; d++) s += hc[d] * Wr[d];
        if (t < 15)      out_predI[(size_t)n * 15 + p] = s;
        else if (t < 30) out_predR[(size_t)n * 15 + p] = s;
        else             s_pr[p] = s;
    }
    __syncthreads();
    if (t == 0) {
        float alpha = 1.f / (1.f + expf(-s_pr[0]));
        float beta  = 1.f / (1.f + expf(-s_pr[1]));
        float Nv = Npop[n];
        float Iv = I0[n], Rv = R0[n];
        float S = Nv - Iv - Rv;
        float SoN = S / Nv;
        for (int st = 0; st < 15; st++) {
            float dIv = alpha * Iv * SoN - beta * Iv;
            float dRv = beta * Iv;
            out_phyI[(size_t)n * 15 + st] = dIv;
            out_phyR[(size_t)n * 15 + st] = dRv;
            Iv += dIv; Rv += dRv;
        }
    }
}

extern "C" void kernel_launch(void* const* d_in, const int* in_sizes, int n_in,
                              void* d_out, int out_size, void* d_ws, size_t ws_size,
                              hipStream_t stream) {
    const float* dynamic = (const float*)d_in[0];
    const int*   ei      = (const int*)d_in[1];
    const float* cI      = (const float*)d_in[2];
    const float* cR      = (const float*)d_in[3];
    const float* Npop    = (const float*)d_in[4];
    const float* I0      = (const float*)d_in[5];
    const float* R0      = (const float*)d_in[6];
    const float* W1      = (const float*)d_in[9];
    const float* a_src1  = (const float*)d_in[10];
    const float* a_dst1  = (const float*)d_in[11];
    const float* b1      = (const float*)d_in[12];
    const float* W2      = (const float*)d_in[13];
    const float* a_src2  = (const float*)d_in[14];
    const float* a_dst2  = (const float*)d_in[15];
    const float* b2      = (const float*)d_in[16];
    const float* W_ih    = (const float*)d_in[17];
    const float* b_ih    = (const float*)d_in[19];
    const float* b_hh    = (const float*)d_in[20];
    const float* W_I     = (const float*)d_in[21];
    const float* b_I     = (const float*)d_in[22];
    const float* W_R     = (const float*)d_in[23];
    const float* b_R     = (const float*)d_in[24];
    const float* W_sir   = (const float*)d_in[25];
    const float* b_sir   = (const float*)d_in[26];
    float* out = (float*)d_out;

    // workspace layout (~65 MB)
    int* wsi = (int*)d_ws;
    int* offs    = wsi;              // 20001 (pad 20096)
    int* cursor  = wsi + 20096;      // 20000 (pad 20096)
    int* csr_src = wsi + 40192;      // 660000 (pad 660096)
    float* fp = (float*)(wsi + 700288);
    float* w1f = fp; fp += 1152;     // 128*8
    float* w2f = fp; fp += 640;      // 256*2
    float* al1 = fp; fp += 80128;    // 20000*4
    float* ar1 = fp; fp += 80128;
    float* al2 = fp; fp += 20096;    // 20000
    float* ar2 = fp; fp += 20096;
    float* buf1 = fp; fp += 10240000; // agg1 [20000][512]; later gi [20000][384] + xl2
    float* buf2 = fp; fp += 5120000;  // x1 [20000][256]; later x2 [20000][128]
    float* agg1 = buf1;
    float* x1   = buf2;
    float* gi   = buf1;               // 7,680,000 floats
    float* xl2  = buf1 + 7680000;     // 2,560,000 floats
    float* x2   = buf2;               // overwrites x1 (dead by then)

    // CSR build
    hipMemsetAsync(cursor, 0, NN * sizeof(int), stream);
    count_deg_kernel<<<(NET + 255) / 256, 256, 0, stream>>>(ei, cursor);
    scan_kernel<<<1, 1024, 0, stream>>>(cursor, offs);
    fill_csr_kernel<<<(NET + 255) / 256, 256, 0, stream>>>(ei, cursor, csr_src);

    // attention-vector folds
    fold_w1<<<1, 128, 0, stream>>>(W1, a_src1, a_dst1, w1f);
    fold_w2<<<1, 256, 0, stream>>>(W2, a_src2, a_dst2, w2f);

    // GAT layer 1: al/ar from folded weights, gather 128-wide dynamic, then head-GEMM
    alar_apply<128, 8><<<5000, 256, 0, stream>>>(dynamic, w1f, al1, ar1);
    gat_gather<4, false><<<NN, 128, 0, stream>>>(dynamic, al1, ar1, offs, csr_src, nullptr, agg1);
    head_gemm_elu<<<dim3(313, 4), 256, 0, stream>>>(agg1, W1, b1, x1);

    // GAT layer 2: xl2 = x1 @ W2; al/ar folded; gather 128-wide xl2 (+bias+ELU fused)
    alar_apply<256, 2><<<5000, 256, 0, stream>>>(x1, w2f, al2, ar2);
    gemm_f32<false><<<dim3(157, 1), 256, 0, stream>>>(x1, W2, xl2, NN, 128, 256);
    gat_gather<1, true><<<NN, 128, 0, stream>>>(xl2, al2, ar2, offs, csr_src, b2, x2);

    // GRU input gates: gi = x2 @ W_ih^T
    gemm_f32<true><<<dim3(157, 3), 256, 0, stream>>>(x2, W_ih, gi, NN, 384, 128);

    // GRU + prediction heads + SIR recurrence
    gru_heads_kernel<<<NN, 128, 0, stream>>>(gi, b_ih, b_hh, cI, cR, Npop, I0, R0,
                                             W_I, b_I, W_R, b_R, W_sir, b_sir,
                                             out, out + 300000, out + 600000,
                                             out + 900000, out + 1200000);
}

// Round 3
// 338.606 us; speedup vs baseline: 1.3548x; 1.1311x over previous
//
#include <hip/hip_runtime.h>

#define NN 20000
#define NE 640000
#define NET (NE + NN)   // 660000 edges incl. self-loops

typedef __attribute__((ext_vector_type(8))) short bf16x8;
typedef __attribute__((ext_vector_type(4))) float f32x4;

__device__ inline ushort f2bf_rne(float x) {
    unsigned u = __float_as_uint(x);
    return (ushort)((u + 0x7FFFu + ((u >> 16) & 1u)) >> 16);
}
__device__ inline float bf2f(ushort u) {
    return __uint_as_float(((unsigned)u) << 16);
}
__device__ inline void split2(float x, ushort& hi, ushort& lo) {
    unsigned u = __float_as_uint(x);
    unsigned r = (u + 0x7FFFu + ((u >> 16) & 1u)) & 0xFFFF0000u;  // RNE to bf16
    hi = (ushort)(r >> 16);
    lo = f2bf_rne(x - __uint_as_float(r));   // x - hi is exact
}

// ---------------- CSR build ----------------
__global__ void count_deg_kernel(const int* __restrict__ ei, int* __restrict__ deg) {
    int e = blockIdx.x * 256 + threadIdx.x;
    if (e < NET) {
        int dst = (e < NE) ? ei[NE + e] : (e - NE);
        atomicAdd(&deg[dst], 1);
    }
}

__global__ void scan_kernel(int* __restrict__ deg_cursor, int* __restrict__ offs) {
    __shared__ int swsum[16], swsum2[16];
    __shared__ int s_carry;
    int t = threadIdx.x, wv = t >> 6, ln = t & 63;
    if (t == 0) s_carry = 0;
    __syncthreads();
    for (int base = 0; base < NN; base += 1024) {
        int i = base + t;
        int orig = (i < NN) ? deg_cursor[i] : 0;
        int v = orig;
#pragma unroll
        for (int o = 1; o < 64; o <<= 1) { int u = __shfl_up(v, o, 64); if (ln >= o) v += u; }
        if (ln == 63) swsum[wv] = v;
        __syncthreads();
        if (t < 16) {
            int sv = swsum[t];
#pragma unroll
            for (int o = 1; o < 16; o <<= 1) { int u = __shfl_up(sv, o, 16); if (t >= o) sv += u; }
            swsum2[t] = sv;
        }
        __syncthreads();
        int excl = s_carry + (wv ? swsum2[wv - 1] : 0) + v - orig;
        if (i < NN) { offs[i] = excl; deg_cursor[i] = excl; }
        __syncthreads();
        if (t == 0) s_carry += swsum2[15];
        __syncthreads();
    }
    if (threadIdx.x == 0) offs[NN] = s_carry;
}

__global__ void fill_csr_kernel(const int* __restrict__ ei, int* __restrict__ cursor,
                                int* __restrict__ csr_src) {
    int e = blockIdx.x * 256 + threadIdx.x;
    if (e < NET) {
        int src, dst;
        if (e < NE) { src = ei[e]; dst = ei[NE + e]; }
        else        { src = dst = e - NE; }
        int pos = atomicAdd(&cursor[dst], 1);
        csr_src[pos] = src;
    }
}

// ---------------- fold attention vectors into input space ----------------
__global__ void fold_w1(const float* __restrict__ W1, const float* __restrict__ a_src,
                        const float* __restrict__ a_dst, float* __restrict__ wf) {
    int k = threadIdx.x;  // 128
#pragma unroll
    for (int h = 0; h < 4; h++) {
        float s1 = 0.f, s2 = 0.f;
        for (int c = 0; c < 64; c++) {
            float w = W1[k * 256 + h * 64 + c];
            s1 += w * a_src[h * 64 + c];
            s2 += w * a_dst[h * 64 + c];
        }
        wf[k * 8 + h] = s1;
        wf[k * 8 + 4 + h] = s2;
    }
}

__global__ void fold_w2(const float* __restrict__ W2, const float* __restrict__ a_src,
                        const float* __restrict__ a_dst, float* __restrict__ wf) {
    int k = threadIdx.x;  // 256
    float s1 = 0.f, s2 = 0.f;
    for (int c = 0; c < 128; c++) {
        float w = W2[k * 128 + c];
        s1 += w * a_src[c];
        s2 += w * a_dst[c];
    }
    wf[k * 2] = s1;
    wf[k * 2 + 1] = s2;
}

// ---------------- layer-1 al/ar + bf16 cast of dynamic (fused) ----------------
__launch_bounds__(256)
__global__ void alar_cast(const float* __restrict__ X, const float* __restrict__ wf,
                          ushort* __restrict__ Xbf, float* __restrict__ al,
                          float* __restrict__ ar) {
    __shared__ float ws[8][128];
    int t = threadIdx.x;
    for (int i = t; i < 1024; i += 256) ws[i & 7][i >> 3] = wf[i];
    __syncthreads();
    int wv = t >> 6, ln = t & 63;
    int n = blockIdx.x * 4 + wv;
    float2 xv = *(const float2*)(X + (size_t)n * 128 + ln * 2);
    ushort2 ub;
    ub.x = f2bf_rne(xv.x);
    ub.y = f2bf_rne(xv.y);
    *(ushort2*)(Xbf + (size_t)n * 128 + ln * 2) = ub;
    float p[8];
#pragma unroll
    for (int o = 0; o < 8; o++) p[o] = xv.x * ws[o][ln * 2] + xv.y * ws[o][ln * 2 + 1];
#pragma unroll
    for (int off = 32; off > 0; off >>= 1)
#pragma unroll
        for (int o = 0; o < 8; o++) p[o] += __shfl_xor(p[o], off, 64);
    if (ln == 0) {
#pragma unroll
        for (int h = 0; h < 4; h++) {
            al[n * 4 + h] = p[h];
            ar[n * 4 + h] = p[4 + h];
        }
    }
}

// ---------------- layer-2 al/ar = x1 @ w2f ----------------
__launch_bounds__(256)
__global__ void alar_apply2(const float* __restrict__ X, const float* __restrict__ wf,
                            float* __restrict__ al, float* __restrict__ ar) {
    __shared__ float ws[2][256];
    int t = threadIdx.x;
    for (int i = t; i < 512; i += 256) ws[i & 1][i >> 1] = wf[i];
    __syncthreads();
    int wv = t >> 6, ln = t & 63;
    int n = blockIdx.x * 4 + wv;
    float p0 = 0.f, p1 = 0.f;
#pragma unroll
    for (int cc = 0; cc < 4; cc++) {
        int c = ln * 4 + cc;  // strided pattern over 256
        float x = X[(size_t)n * 256 + c];
        p0 += x * ws[0][c];
        p1 += x * ws[1][c];
    }
#pragma unroll
    for (int off = 32; off > 0; off >>= 1) {
        p0 += __shfl_xor(p0, off, 64);
        p1 += __shfl_xor(p1, off, 64);
    }
    if (ln == 0) { al[n] = p0; ar[n] = p1; }
}

// ---------------- GAT gather (bf16 X), online softmax ----------------
// FUSE: +bias+ELU, f32 out [NN][128]. !FUSE: bf16 out [NN][HEADS*128].
template <int HEADS, bool FUSE>
__launch_bounds__(128)
__global__ void gat_gather(const ushort* __restrict__ X, const float* __restrict__ al,
                           const float* __restrict__ ar, const int* __restrict__ offs,
                           const int* __restrict__ csr, const float* __restrict__ bias,
                           void* __restrict__ outp) {
    constexpr int CHUNK = 256;
    int n = blockIdx.x, t = threadIdx.x;
    int wv = t >> 6, ln = t & 63;
    int e0 = offs[n], e1 = offs[n + 1];
    __shared__ int s_src[CHUNK];
    __shared__ float s_w[CHUNK][HEADS];
    __shared__ float s_red[2][HEADS];

    float arv[HEADS], m[HEADS], srun[HEADS], accA[HEADS], accB[HEADS];
#pragma unroll
    for (int h = 0; h < HEADS; h++) {
        arv[h] = ar[n * HEADS + h];
        m[h] = -1e30f; srun[h] = 0.f; accA[h] = 0.f; accB[h] = 0.f;
    }

    for (int base = e0; base < e1; base += CHUNK) {
        int cnt = min(CHUNK, e1 - base);
        float lmx[HEADS];
#pragma unroll
        for (int h = 0; h < HEADS; h++) lmx[h] = -1e30f;
        for (int idx = t; idx < cnt; idx += 128) {
            int s = csr[base + idx];
            s_src[idx] = s;
#pragma unroll
            for (int h = 0; h < HEADS; h++) {
                float lg = al[s * HEADS + h] + arv[h];
                lg = lg > 0.f ? lg : 0.2f * lg;
                s_w[idx][h] = lg;
                lmx[h] = fmaxf(lmx[h], lg);
            }
        }
#pragma unroll
        for (int off = 32; off > 0; off >>= 1)
#pragma unroll
            for (int h = 0; h < HEADS; h++) lmx[h] = fmaxf(lmx[h], __shfl_xor(lmx[h], off, 64));
        if (ln == 0)
#pragma unroll
            for (int h = 0; h < HEADS; h++) s_red[wv][h] = lmx[h];
        __syncthreads();
        float mn[HEADS];
#pragma unroll
        for (int h = 0; h < HEADS; h++) mn[h] = fmaxf(fmaxf(s_red[0][h], s_red[1][h]), m[h]);
#pragma unroll
        for (int h = 0; h < HEADS; h++) {
            float sc = expf(m[h] - mn[h]);
            accA[h] *= sc; accB[h] *= sc; srun[h] *= sc; m[h] = mn[h];
        }
        float ls[HEADS];
#pragma unroll
        for (int h = 0; h < HEADS; h++) ls[h] = 0.f;
        for (int idx = t; idx < cnt; idx += 128) {
#pragma unroll
            for (int h = 0; h < HEADS; h++) {
                float w = expf(s_w[idx][h] - m[h]);
                s_w[idx][h] = w;
                ls[h] += w;
            }
        }
#pragma unroll
        for (int off = 32; off > 0; off >>= 1)
#pragma unroll
            for (int h = 0; h < HEADS; h++) ls[h] += __shfl_xor(ls[h], off, 64);
        __syncthreads();
        if (ln == 0)
#pragma unroll
            for (int h = 0; h < HEADS; h++) s_red[wv][h] = ls[h];
        __syncthreads();
#pragma unroll
        for (int h = 0; h < HEADS; h++) srun[h] += s_red[0][h] + s_red[1][h];
        // gather (bf16 rows)
        int k = 0;
        for (; k + 4 <= cnt; k += 4) {
            ushort u0 = X[((size_t)s_src[k + 0] << 7) + t];
            ushort u1 = X[((size_t)s_src[k + 1] << 7) + t];
            ushort u2 = X[((size_t)s_src[k + 2] << 7) + t];
            ushort u3 = X[((size_t)s_src[k + 3] << 7) + t];
            float x0 = bf2f(u0), x1 = bf2f(u1), x2 = bf2f(u2), x3 = bf2f(u3);
#pragma unroll
            for (int h = 0; h < HEADS; h++) {
                accA[h] = fmaf(s_w[k + 0][h], x0, accA[h]);
                accB[h] = fmaf(s_w[k + 1][h], x1, accB[h]);
                accA[h] = fmaf(s_w[k + 2][h], x2, accA[h]);
                accB[h] = fmaf(s_w[k + 3][h], x3, accB[h]);
            }
        }
        for (; k < cnt; k++) {
            float x0 = bf2f(X[((size_t)s_src[k] << 7) + t]);
#pragma unroll
            for (int h = 0; h < HEADS; h++) accA[h] = fmaf(s_w[k][h], x0, accA[h]);
        }
        __syncthreads();
    }
    if (FUSE) {
        float* out = (float*)outp;
        float o = (accA[0] + accB[0]) / srun[0] + bias[t];
        out[(size_t)n * 128 + t] = o > 0.f ? o : (expf(o) - 1.f);
    } else {
        ushort* out = (ushort*)outp;
#pragma unroll
        for (int h = 0; h < HEADS; h++)
            out[(size_t)n * (HEADS * 128) + h * 128 + t] = f2bf_rne((accA[h] + accB[h]) / srun[h]);
    }
}

// ---------------- MFMA split-bf16 GEMM ----------------
// C[M,Ntot] = act(A @ B + bias). BM=128, BK=64, 256 threads (2x2 waves).
// ASPLIT=1: A f32, split hi/lo (3-term). ASPLIT=0: A already bf16 (2-term).
// BT=false: B f32 [K][ldb], col base z*zB + blockIdx.y*BN.
// BT=true:  B f32 [N][ldb] (transposed logical), row = blockIdx.y*BN + n.
// ACT=1: +bias, ELU. OUTBF: bf16 output.
template <int ASPLIT, bool BT, int ACT, bool OUTBF, int BN>
__launch_bounds__(256)
__global__ void gemm3t(const void* __restrict__ Aptr, const float* __restrict__ B,
                       const float* __restrict__ bias, void* __restrict__ Cptr,
                       int M, int K, int lda, int ldb, int ldc, int zA, int zB, int zC) {
    constexpr int NF = BN / 32;
    __shared__ ushort Ah[128 * 64];
    __shared__ ushort Al[ASPLIT ? 128 * 64 : 64];
    __shared__ ushort Bh[64 * BN];
    __shared__ ushort Bl[64 * BN];
    int tid = threadIdx.x;
    int z = blockIdx.z;
    int bm = blockIdx.x * 128;
    int ny = blockIdx.y * BN;
    int wid = tid >> 6, ln = tid & 63;
    int wm = wid >> 1, wn = wid & 1;
    f32x4 acc[4][NF];
#pragma unroll
    for (int a = 0; a < 4; a++)
#pragma unroll
        for (int b = 0; b < NF; b++)
#pragma unroll
            for (int j = 0; j < 4; j++) acc[a][b][j] = 0.f;
    const float* Af = (const float*)Aptr;
    const ushort* Au = (const ushort*)Aptr;
    size_t abase = (size_t)z * zA;
    int bcb = z * zB + ny;

    for (int k0 = 0; k0 < K; k0 += 64) {
        // ---- stage A (128 x 64) ----
#pragma unroll
        for (int i = 0; i < 8; i++) {
            int idx = tid + i * 256;
            int r = idx >> 4, c4 = (idx & 15) * 4;
            int gr = bm + r;
            int ab = (r * 128 + c4 * 2) ^ ((r & 7) << 4);
            if (ASPLIT) {
                float4 v = make_float4(0.f, 0.f, 0.f, 0.f);
                if (gr < M) v = *(const float4*)(Af + abase + (size_t)gr * lda + k0 + c4);
                ushort h0, h1, h2, h3, l0, l1, l2, l3;
                split2(v.x, h0, l0); split2(v.y, h1, l1);
                split2(v.z, h2, l2); split2(v.w, h3, l3);
                *(ushort4*)((char*)Ah + ab) = make_ushort4(h0, h1, h2, h3);
                *(ushort4*)((char*)Al + ab) = make_ushort4(l0, l1, l2, l3);
            } else {
                ushort4 v = make_ushort4(0, 0, 0, 0);
                if (gr < M) v = *(const ushort4*)(Au + abase + (size_t)gr * lda + k0 + c4);
                *(ushort4*)((char*)Ah + ab) = v;
            }
        }
        // ---- stage B (64 x BN) ----
        if (!BT) {
#pragma unroll
            for (int i = 0; i < BN / 16; i++) {
                int idx = tid + i * 256;
                int kk = idx / (BN / 4);
                int c4 = (idx % (BN / 4)) * 4;
                float4 v = *(const float4*)(B + (size_t)(k0 + kk) * ldb + bcb + c4);
                float vv[4] = {v.x, v.y, v.z, v.w};
#pragma unroll
                for (int q = 0; q < 4; q++) {
                    int nl = c4 + q;
                    int bb = (nl * 128 + kk * 2) ^ ((nl & 7) << 4);
                    ushort h, l;
                    split2(vv[q], h, l);
                    *(ushort*)((char*)Bh + bb) = h;
                    *(ushort*)((char*)Bl + bb) = l;
                }
            }
        } else {
#pragma unroll
            for (int i = 0; i < BN / 16; i++) {
                int idx = tid + i * 256;
                int nl = idx >> 4, k4 = (idx & 15) * 4;
                float4 v = *(const float4*)(B + (size_t)(ny + nl) * ldb + k0 + k4);
                ushort h0, h1, h2, h3, l0, l1, l2, l3;
                split2(v.x, h0, l0); split2(v.y, h1, l1);
                split2(v.z, h2, l2); split2(v.w, h3, l3);
                int bb = (nl * 128 + k4 * 2) ^ ((nl & 7) << 4);
                *(ushort4*)((char*)Bh + bb) = make_ushort4(h0, h1, h2, h3);
                *(ushort4*)((char*)Bl + bb) = make_ushort4(l0, l1, l2, l3);
            }
        }
        __syncthreads();
        // ---- compute ----
#pragma unroll
        for (int ks = 0; ks < 2; ks++) {
            int kb = ks * 64 + (ln >> 4) * 16;  // byte offset of this lane's k-group
            bf16x8 ah[4], alo[ASPLIT ? 4 : 1], bh[NF], bl[NF];
#pragma unroll
            for (int mf = 0; mf < 4; mf++) {
                int r = wm * 64 + mf * 16 + (ln & 15);
                int ab = (r * 128 + kb) ^ ((r & 7) << 4);
                ah[mf] = *(bf16x8*)((char*)Ah + ab);
                if (ASPLIT) alo[mf] = *(bf16x8*)((char*)Al + ab);
            }
#pragma unroll
            for (int nf = 0; nf < NF; nf++) {
                int nl = wn * (BN / 2) + nf * 16 + (ln & 15);
                int bb = (nl * 128 + kb) ^ ((nl & 7) << 4);
                bh[nf] = *(bf16x8*)((char*)Bh + bb);
                bl[nf] = *(bf16x8*)((char*)Bl + bb);
            }
#pragma unroll
            for (int mf = 0; mf < 4; mf++)
#pragma unroll
                for (int nf = 0; nf < NF; nf++) {
                    acc[mf][nf] = __builtin_amdgcn_mfma_f32_16x16x32_bf16(ah[mf], bh[nf], acc[mf][nf], 0, 0, 0);
                    acc[mf][nf] = __builtin_amdgcn_mfma_f32_16x16x32_bf16(ah[mf], bl[nf], acc[mf][nf], 0, 0, 0);
                    if (ASPLIT)
                        acc[mf][nf] = __builtin_amdgcn_mfma_f32_16x16x32_bf16(alo[mf], bh[nf], acc[mf][nf], 0, 0, 0);
                }
        }
        __syncthreads();
    }
    // ---- epilogue ----
    float* Cf = (float*)Cptr;
    ushort* Cu = (ushort*)Cptr;
#pragma unroll
    for (int mf = 0; mf < 4; mf++)
#pragma unroll
        for (int nf = 0; nf < NF; nf++) {
            int colL = ny + wn * (BN / 2) + nf * 16 + (ln & 15);
#pragma unroll
            for (int j = 0; j < 4; j++) {
                int row = bm + wm * 64 + mf * 16 + (ln >> 4) * 4 + j;
                if (row < M) {
                    float v = acc[mf][nf][j];
                    if (ACT) {
                        v += bias[z * zC + colL];
                        v = v > 0.f ? v : (expf(v) - 1.f);
                    }
                    size_t ci = (size_t)row * ldc + z * zC + colL;
                    if (OUTBF) Cu[ci] = f2bf_rne(v);
                    else       Cf[ci] = v;
                }
            }
        }
}

// ---------------- GRU (h0=0) + heads + SIR physics ----------------
__launch_bounds__(128)
__global__ void gru_heads_kernel(const float* __restrict__ gi, const float* __restrict__ b_ih,
                                 const float* __restrict__ b_hh, const float* __restrict__ cI,
                                 const float* __restrict__ cR, const float* __restrict__ Npop,
                                 const float* __restrict__ I0, const float* __restrict__ R0,
                                 const float* __restrict__ W_I, const float* __restrict__ b_I,
                                 const float* __restrict__ W_R, const float* __restrict__ b_R,
                                 const float* __restrict__ W_sir, const float* __restrict__ b_sir,
                                 float* __restrict__ out_predI, float* __restrict__ out_predR,
                                 float* __restrict__ out_phyI, float* __restrict__ out_phyR,
                                 float* __restrict__ out_h) {
    int n = blockIdx.x, t = threadIdx.x;
    __shared__ float hc[130];
    __shared__ float s_pr[2];
    const float* g = gi + (size_t)n * 384;
    float ir = g[t] + b_ih[t];
    float iz = g[128 + t] + b_ih[128 + t];
    float ih = g[256 + t] + b_ih[256 + t];
    float r = 1.f / (1.f + expf(-(ir + b_hh[t])));
    float z = 1.f / (1.f + expf(-(iz + b_hh[128 + t])));
    float nn = tanhf(ih + r * b_hh[256 + t]);
    float hv = (1.f - z) * nn;
    out_h[(size_t)n * 128 + t] = hv;
    hc[t] = hv;
    if (t == 0) { hc[128] = cI[n]; hc[129] = cR[n]; }
    __syncthreads();
    if (t < 32) {
        const float* Wr;
        float bb;
        int p;
        if (t < 15)      { p = t;      Wr = W_I + p * 130;   bb = b_I[p]; }
        else if (t < 30) { p = t - 15; Wr = W_R + p * 130;   bb = b_R[p]; }
        else             { p = t - 30; Wr = W_sir + p * 130; bb = b_sir[p]; }
        float s = bb;
        for (int d = 0; d < 130; d++) s += hc[d] * Wr[d];
        if (t < 15)      out_predI[(size_t)n * 15 + p] = s;
        else if (t < 30) out_predR[(size_t)n * 15 + p] = s;
        else             s_pr[p] = s;
    }
    __syncthreads();
    if (t == 0) {
        float alpha = 1.f / (1.f + expf(-s_pr[0]));
        float beta  = 1.f / (1.f + expf(-s_pr[1]));
        float Nv = Npop[n];
        float Iv = I0[n], Rv = R0[n];
        float S = Nv - Iv - Rv;
        float SoN = S / Nv;
        for (int st = 0; st < 15; st++) {
            float dIv = alpha * Iv * SoN - beta * Iv;
            float dRv = beta * Iv;
            out_phyI[(size_t)n * 15 + st] = dIv;
            out_phyR[(size_t)n * 15 + st] = dRv;
            Iv += dIv; Rv += dRv;
        }
    }
}

extern "C" void kernel_launch(void* const* d_in, const int* in_sizes, int n_in,
                              void* d_out, int out_size, void* d_ws, size_t ws_size,
                              hipStream_t stream) {
    const float* dynamic = (const float*)d_in[0];
    const int*   ei      = (const int*)d_in[1];
    const float* cI      = (const float*)d_in[2];
    const float* cR      = (const float*)d_in[3];
    const float* Npop    = (const float*)d_in[4];
    const float* I0      = (const float*)d_in[5];
    const float* R0      = (const float*)d_in[6];
    const float* W1      = (const float*)d_in[9];
    const float* a_src1  = (const float*)d_in[10];
    const float* a_dst1  = (const float*)d_in[11];
    const float* b1      = (const float*)d_in[12];
    const float* W2      = (const float*)d_in[13];
    const float* a_src2  = (const float*)d_in[14];
    const float* a_dst2  = (const float*)d_in[15];
    const float* b2      = (const float*)d_in[16];
    const float* W_ih    = (const float*)d_in[17];
    const float* b_ih    = (const float*)d_in[19];
    const float* b_hh    = (const float*)d_in[20];
    const float* W_I     = (const float*)d_in[21];
    const float* b_I     = (const float*)d_in[22];
    const float* W_R     = (const float*)d_in[23];
    const float* b_R     = (const float*)d_in[24];
    const float* W_sir   = (const float*)d_in[25];
    const float* b_sir   = (const float*)d_in[26];
    float* out = (float*)d_out;

    // ---- workspace layout (~60 MB) ----
    int* wsi = (int*)d_ws;
    int* offs    = wsi;              // 20001 (pad 20096)
    int* cursor  = wsi + 20096;      // 20000 (pad 20096)
    int* csr_src = wsi + 40192;      // 660000 (pad 660096)
    float* fp = (float*)(wsi + 700288);
    float* w1f = fp; fp += 1152;     // 128*8
    float* w2f = fp; fp += 640;      // 256*2
    float* al1 = fp; fp += 80128;    // 20000*4
    float* ar1 = fp; fp += 80128;
    float* al2 = fp; fp += 20096;
    float* ar2 = fp; fp += 20096;
    ushort* dyn_bf = (ushort*)fp; fp += 1280000;   // 20000*128 bf16
    float* x1 = fp; fp += 5120000;                 // [20000][256] f32; later x2 [20000][128]
    float* R  = fp; fp += 7680000;                 // agg_bf / xl2_bf / gi
    ushort* agg_bf = (ushort*)R;                   // [20000][512] bf16 (20.5 MB)
    ushort* xl2_bf = (ushort*)R;                   // [20000][128] bf16 (after agg dead)
    float* gi = R;                                 // [20000][384] f32 (after xl2 dead)
    float* x2 = x1;                                // [20000][128] f32 (after x1 dead)

    // CSR build
    hipMemsetAsync(cursor, 0, NN * sizeof(int), stream);
    count_deg_kernel<<<(NET + 255) / 256, 256, 0, stream>>>(ei, cursor);
    scan_kernel<<<1, 1024, 0, stream>>>(cursor, offs);
    fill_csr_kernel<<<(NET + 255) / 256, 256, 0, stream>>>(ei, cursor, csr_src);

    // attention-vector folds
    fold_w1<<<1, 128, 0, stream>>>(W1, a_src1, a_dst1, w1f);
    fold_w2<<<1, 256, 0, stream>>>(W2, a_src2, a_dst2, w2f);

    // GAT layer 1
    alar_cast<<<5000, 256, 0, stream>>>(dynamic, w1f, dyn_bf, al1, ar1);
    gat_gather<4, false><<<NN, 128, 0, stream>>>(dyn_bf, al1, ar1, offs, csr_src, nullptr, agg_bf);
    // x1 = ELU(agg_bf @ W1 + b1) per head: A bf16 (2-term), grid.z = head
    gemm3t<0, false, 1, false, 64><<<dim3(157, 1, 4), 256, 0, stream>>>(
        agg_bf, W1, b1, x1, NN, 128, 512, 256, 256, 128, 64, 64);

    // GAT layer 2
    alar_apply2<<<5000, 256, 0, stream>>>(x1, w2f, al2, ar2);
    // xl2_bf = x1 @ W2 (3-term, bf16 out)
    gemm3t<1, false, 0, true, 128><<<dim3(157, 1, 1), 256, 0, stream>>>(
        x1, W2, nullptr, xl2_bf, NN, 256, 256, 128, 128, 0, 0, 0);
    gat_gather<1, true><<<NN, 128, 0, stream>>>(xl2_bf, al2, ar2, offs, csr_src, b2, x2);

    // gi = x2 @ W_ih^T (3-term, BT)
    gemm3t<1, true, 0, false, 128><<<dim3(157, 3, 1), 256, 0, stream>>>(
        x2, W_ih, nullptr, gi, NN, 128, 128, 128, 384, 0, 0, 0);

    // GRU + prediction heads + SIR
    gru_heads_kernel<<<NN, 128, 0, stream>>>(gi, b_ih, b_hh, cI, cR, Npop, I0, R0,
                                             W_I, b_I, W_R, b_R, W_sir, b_sir,
                                             out, out + 300000, out + 600000,
                                             out + 900000, out + 1200000);
}

// Round 4
// 302.254 us; speedup vs baseline: 1.5177x; 1.1203x over previous
//
#include <hip/hip_runtime.h>

#define NN 20000
#define NE 640000
#define NET (NE + NN)   // 660000 edges incl. self-loops

typedef __attribute__((ext_vector_type(8))) short bf16x8;
typedef __attribute__((ext_vector_type(4))) float f32x4;

__device__ inline ushort f2bf_rne(float x) {
    unsigned u = __float_as_uint(x);
    return (ushort)((u + 0x7FFFu + ((u >> 16) & 1u)) >> 16);
}
__device__ inline float bf2f(ushort u) {
    return __uint_as_float(((unsigned)u) << 16);
}
__device__ inline void split2(float x, ushort& hi, ushort& lo) {
    unsigned u = __float_as_uint(x);
    unsigned r = (u + 0x7FFFu + ((u >> 16) & 1u)) & 0xFFFF0000u;  // RNE to bf16
    hi = (ushort)(r >> 16);
    lo = f2bf_rne(x - __uint_as_float(r));   // x - hi is exact
}

// ---------------- pre1: count_deg + fold_w1 + fold_w2 (independent) ----------------
__global__ void pre1_kernel(const int* __restrict__ ei, int* __restrict__ deg,
                            const float* __restrict__ W1, const float* __restrict__ as1,
                            const float* __restrict__ ad1, float* __restrict__ w1f,
                            const float* __restrict__ W2, const float* __restrict__ as2,
                            const float* __restrict__ ad2, float* __restrict__ w2f) {
    int b = blockIdx.x, t = threadIdx.x;
    if (b < 2579) {
        int e = b * 256 + t;
        if (e < NET) {
            int dst = (e < NE) ? ei[NE + e] : (e - NE);
            atomicAdd(&deg[dst], 1);
        }
    } else if (b == 2579) {
        if (t < 128) {
            int k = t;
#pragma unroll
            for (int h = 0; h < 4; h++) {
                float s1 = 0.f, s2 = 0.f;
                for (int c = 0; c < 64; c++) {
                    float w = W1[k * 256 + h * 64 + c];
                    s1 += w * as1[h * 64 + c];
                    s2 += w * ad1[h * 64 + c];
                }
                w1f[k * 8 + h] = s1;
                w1f[k * 8 + 4 + h] = s2;
            }
        }
    } else {
        int k = t;  // 256
        float s1 = 0.f, s2 = 0.f;
        for (int c = 0; c < 128; c++) {
            float w = W2[k * 128 + c];
            s1 += w * as2[c];
            s2 += w * ad2[c];
        }
        w2f[k * 2] = s1;
        w2f[k * 2 + 1] = s2;
    }
}

// ---------------- scan ----------------
__global__ void scan_kernel(int* __restrict__ deg_cursor, int* __restrict__ offs) {
    __shared__ int swsum[16], swsum2[16];
    __shared__ int s_carry;
    int t = threadIdx.x, wv = t >> 6, ln = t & 63;
    if (t == 0) s_carry = 0;
    __syncthreads();
    for (int base = 0; base < NN; base += 1024) {
        int i = base + t;
        int orig = (i < NN) ? deg_cursor[i] : 0;
        int v = orig;
#pragma unroll
        for (int o = 1; o < 64; o <<= 1) { int u = __shfl_up(v, o, 64); if (ln >= o) v += u; }
        if (ln == 63) swsum[wv] = v;
        __syncthreads();
        if (t < 16) {
            int sv = swsum[t];
#pragma unroll
            for (int o = 1; o < 16; o <<= 1) { int u = __shfl_up(sv, o, 16); if (t >= o) sv += u; }
            swsum2[t] = sv;
        }
        __syncthreads();
        int excl = s_carry + (wv ? swsum2[wv - 1] : 0) + v - orig;
        if (i < NN) { offs[i] = excl; deg_cursor[i] = excl; }
        __syncthreads();
        if (t == 0) s_carry += swsum2[15];
        __syncthreads();
    }
    if (threadIdx.x == 0) offs[NN] = s_carry;
}

// ---------------- pre2: fill_csr + alar_cast (independent) ----------------
__global__ void pre2_kernel(const int* __restrict__ ei, int* __restrict__ cursor,
                            int* __restrict__ csr_src, const float* __restrict__ X,
                            const float* __restrict__ wf, ushort* __restrict__ Xbf,
                            float* __restrict__ al, float* __restrict__ ar) {
    __shared__ float ws[8][128];
    int b = blockIdx.x, t = threadIdx.x;
    if (b < 2579) {
        int e = b * 256 + t;
        if (e < NET) {
            int src, dst;
            if (e < NE) { src = ei[e]; dst = ei[NE + e]; }
            else        { src = dst = e - NE; }
            int pos = atomicAdd(&cursor[dst], 1);
            csr_src[pos] = src;
        }
    } else {
        for (int i = t; i < 1024; i += 256) ws[i & 7][i >> 3] = wf[i];
        __syncthreads();
        int wv = t >> 6, ln = t & 63;
        int n = (b - 2579) * 4 + wv;
        float2 xv = *(const float2*)(X + (size_t)n * 128 + ln * 2);
        ushort2 ub;
        ub.x = f2bf_rne(xv.x);
        ub.y = f2bf_rne(xv.y);
        *(ushort2*)(Xbf + (size_t)n * 128 + ln * 2) = ub;
        float p[8];
#pragma unroll
        for (int o = 0; o < 8; o++) p[o] = xv.x * ws[o][ln * 2] + xv.y * ws[o][ln * 2 + 1];
#pragma unroll
        for (int off = 32; off > 0; off >>= 1)
#pragma unroll
            for (int o = 0; o < 8; o++) p[o] += __shfl_xor(p[o], off, 64);
        if (ln == 0) {
#pragma unroll
            for (int h = 0; h < 4; h++) {
                al[n * 4 + h] = p[h];
                ar[n * 4 + h] = p[4 + h];
            }
        }
    }
}

// ---------------- layer-2 al/ar = x1 @ w2f ----------------
__launch_bounds__(256)
__global__ void alar_apply2(const float* __restrict__ X, const float* __restrict__ wf,
                            float* __restrict__ al, float* __restrict__ ar) {
    __shared__ float ws[2][256];
    int t = threadIdx.x;
    for (int i = t; i < 512; i += 256) ws[i & 1][i >> 1] = wf[i];
    __syncthreads();
    int wv = t >> 6, ln = t & 63;
    int n = blockIdx.x * 4 + wv;
    float p0 = 0.f, p1 = 0.f;
#pragma unroll
    for (int cc = 0; cc < 4; cc++) {
        int c = ln * 4 + cc;
        float x = X[(size_t)n * 256 + c];
        p0 += x * ws[0][c];
        p1 += x * ws[1][c];
    }
#pragma unroll
    for (int off = 32; off > 0; off >>= 1) {
        p0 += __shfl_xor(p0, off, 64);
        p1 += __shfl_xor(p1, off, 64);
    }
    if (ln == 0) { al[n] = p0; ar[n] = p1; }
}

// ---------------- GAT gather: half-wave per node, register-only softmax ----------------
// 256 threads = 4 waves = 8 nodes/block. Lane owns 4 channels (ushort4/8B loads).
// FUSE: +bias+ELU, f32 out [NN][128]. !FUSE: bf16 out [NN][H*128].
template <int H, bool FUSE>
__launch_bounds__(256)
__global__ void gat_gather_w(const ushort* __restrict__ X, const float* __restrict__ al,
                             const float* __restrict__ ar, const int* __restrict__ offs,
                             const int* __restrict__ csr, const float* __restrict__ bias,
                             void* __restrict__ outp) {
    int t = threadIdx.x;
    int wv = t >> 6, ln = t & 63;
    int hw = ln >> 5, l32 = ln & 31;
    int n = blockIdx.x * 8 + wv * 2 + hw;
    int e0 = offs[n], e1 = offs[n + 1];

    float arv[H], m[H], srun[H], acc[4][H];
#pragma unroll
    for (int h = 0; h < H; h++) {
        arv[h] = ar[n * H + h];
        m[h] = -1e30f; srun[h] = 0.f;
#pragma unroll
        for (int c = 0; c < 4; c++) acc[c][h] = 0.f;
    }
    const ushort* Xc = X + (size_t)l32 * 4;

    for (int base = e0; base < e1; base += 64) {
        int cnt = e1 - base; if (cnt > 64) cnt = 64;
        bool vA = l32 < cnt, vB = l32 + 32 < cnt;
        int srcA = 0, srcB = 0;
        float wA[H], wB[H], lmx[H];
#pragma unroll
        for (int h = 0; h < H; h++) { lmx[h] = -1e30f; wA[h] = 0.f; wB[h] = 0.f; }
        if (vA) {
            srcA = csr[base + l32];
            float av[H];
            if (H == 4) {
                float4 a4 = *(const float4*)(al + (size_t)srcA * 4);
                av[0] = a4.x; av[H > 1 ? 1 : 0] = a4.y;
                av[H > 2 ? 2 : 0] = a4.z; av[H > 3 ? 3 : 0] = a4.w;
            } else {
                av[0] = al[srcA];
            }
#pragma unroll
            for (int h = 0; h < H; h++) {
                float lg = av[h] + arv[h];
                lg = lg > 0.f ? lg : 0.2f * lg;
                wA[h] = lg;
                lmx[h] = fmaxf(lmx[h], lg);
            }
        }
        if (vB) {
            srcB = csr[base + l32 + 32];
            float av[H];
            if (H == 4) {
                float4 a4 = *(const float4*)(al + (size_t)srcB * 4);
                av[0] = a4.x; av[H > 1 ? 1 : 0] = a4.y;
                av[H > 2 ? 2 : 0] = a4.z; av[H > 3 ? 3 : 0] = a4.w;
            } else {
                av[0] = al[srcB];
            }
#pragma unroll
            for (int h = 0; h < H; h++) {
                float lg = av[h] + arv[h];
                lg = lg > 0.f ? lg : 0.2f * lg;
                wB[h] = lg;
                lmx[h] = fmaxf(lmx[h], lg);
            }
        }
        // half-wave max reduce
#pragma unroll
        for (int off = 16; off > 0; off >>= 1)
#pragma unroll
            for (int h = 0; h < H; h++) lmx[h] = fmaxf(lmx[h], __shfl_xor(lmx[h], off, 32));
        // rescale running state + exponentiate weights
        float ls[H];
#pragma unroll
        for (int h = 0; h < H; h++) {
            float mn = fmaxf(m[h], lmx[h]);
            float sc = __expf(m[h] - mn);   // 0 on first chunk
            m[h] = mn;
            srun[h] *= sc;
#pragma unroll
            for (int c = 0; c < 4; c++) acc[c][h] *= sc;
            float a = vA ? __expf(wA[h] - mn) : 0.f;
            float b = vB ? __expf(wB[h] - mn) : 0.f;
            wA[h] = a; wB[h] = b;
            ls[h] = a + b;
        }
#pragma unroll
        for (int off = 16; off > 0; off >>= 1)
#pragma unroll
            for (int h = 0; h < H; h++) ls[h] += __shfl_xor(ls[h], off, 32);
#pragma unroll
        for (int h = 0; h < H; h++) srun[h] += ls[h];

        // gather: weights/rows broadcast from registers, 4 loads in flight
        int k = 0;
        for (; k + 4 <= cnt; k += 4) {
            int r4[4]; float w4[4][H];
            if (k < 32) {
#pragma unroll
                for (int q = 0; q < 4; q++) {
                    r4[q] = __shfl(srcA, k + q, 32);
#pragma unroll
                    for (int h = 0; h < H; h++) w4[q][h] = __shfl(wA[h], k + q, 32);
                }
            } else {
#pragma unroll
                for (int q = 0; q < 4; q++) {
                    r4[q] = __shfl(srcB, k - 32 + q, 32);
#pragma unroll
                    for (int h = 0; h < H; h++) w4[q][h] = __shfl(wB[h], k - 32 + q, 32);
                }
            }
            uint2 u[4];
#pragma unroll
            for (int q = 0; q < 4; q++) u[q] = *(const uint2*)(Xc + (size_t)r4[q] * 128);
#pragma unroll
            for (int q = 0; q < 4; q++) {
                float x0 = __uint_as_float(u[q].x << 16);
                float x1 = __uint_as_float(u[q].x & 0xffff0000u);
                float x2 = __uint_as_float(u[q].y << 16);
                float x3 = __uint_as_float(u[q].y & 0xffff0000u);
#pragma unroll
                for (int h = 0; h < H; h++) {
                    acc[0][h] = fmaf(w4[q][h], x0, acc[0][h]);
                    acc[1][h] = fmaf(w4[q][h], x1, acc[1][h]);
                    acc[2][h] = fmaf(w4[q][h], x2, acc[2][h]);
                    acc[3][h] = fmaf(w4[q][h], x3, acc[3][h]);
                }
            }
        }
        for (; k < cnt; k++) {
            int r; float wk[H];
            if (k < 32) {
                r = __shfl(srcA, k, 32);
#pragma unroll
                for (int h = 0; h < H; h++) wk[h] = __shfl(wA[h], k, 32);
            } else {
                r = __shfl(srcB, k - 32, 32);
#pragma unroll
                for (int h = 0; h < H; h++) wk[h] = __shfl(wB[h], k - 32, 32);
            }
            uint2 u = *(const uint2*)(Xc + (size_t)r * 128);
            float x0 = __uint_as_float(u.x << 16);
            float x1 = __uint_as_float(u.x & 0xffff0000u);
            float x2 = __uint_as_float(u.y << 16);
            float x3 = __uint_as_float(u.y & 0xffff0000u);
#pragma unroll
            for (int h = 0; h < H; h++) {
                acc[0][h] = fmaf(wk[h], x0, acc[0][h]);
                acc[1][h] = fmaf(wk[h], x1, acc[1][h]);
                acc[2][h] = fmaf(wk[h], x2, acc[2][h]);
                acc[3][h] = fmaf(wk[h], x3, acc[3][h]);
            }
        }
    }
    if (FUSE) {
        float* out = (float*)outp;
        float inv = 1.f / srun[0];
        const float* bp = bias + l32 * 4;
        float4 o;
        float v0 = acc[0][0] * inv + bp[0];
        float v1 = acc[1][0] * inv + bp[1];
        float v2 = acc[2][0] * inv + bp[2];
        float v3 = acc[3][0] * inv + bp[3];
        o.x = v0 > 0.f ? v0 : __expf(v0) - 1.f;
        o.y = v1 > 0.f ? v1 : __expf(v1) - 1.f;
        o.z = v2 > 0.f ? v2 : __expf(v2) - 1.f;
        o.w = v3 > 0.f ? v3 : __expf(v3) - 1.f;
        *(float4*)(out + (size_t)n * 128 + l32 * 4) = o;
    } else {
        ushort* out = (ushort*)outp;
#pragma unroll
        for (int h = 0; h < H; h++) {
            float inv = 1.f / srun[h];
            ushort4 o = make_ushort4(f2bf_rne(acc[0][h] * inv), f2bf_rne(acc[1][h] * inv),
                                     f2bf_rne(acc[2][h] * inv), f2bf_rne(acc[3][h] * inv));
            *(ushort4*)(out + (size_t)n * (H * 128) + h * 128 + l32 * 4) = o;
        }
    }
}

// ---------------- MFMA split-bf16 GEMM ----------------
template <int ASPLIT, bool BT, int ACT, bool OUTBF, int BN>
__launch_bounds__(256)
__global__ void gemm3t(const void* __restrict__ Aptr, const float* __restrict__ B,
                       const float* __restrict__ bias, void* __restrict__ Cptr,
                       int M, int K, int lda, int ldb, int ldc, int zA, int zB, int zC) {
    constexpr int NF = BN / 32;
    __shared__ ushort Ah[128 * 64];
    __shared__ ushort Al[ASPLIT ? 128 * 64 : 64];
    __shared__ ushort Bh[64 * BN];
    __shared__ ushort Bl[64 * BN];
    int tid = threadIdx.x;
    int z = blockIdx.z;
    int bm = blockIdx.x * 128;
    int ny = blockIdx.y * BN;
    int wid = tid >> 6, ln = tid & 63;
    int wm = wid >> 1, wn = wid & 1;
    f32x4 acc[4][NF];
#pragma unroll
    for (int a = 0; a < 4; a++)
#pragma unroll
        for (int b = 0; b < NF; b++)
#pragma unroll
            for (int j = 0; j < 4; j++) acc[a][b][j] = 0.f;
    const float* Af = (const float*)Aptr;
    const ushort* Au = (const ushort*)Aptr;
    size_t abase = (size_t)z * zA;
    int bcb = z * zB + ny;

    for (int k0 = 0; k0 < K; k0 += 64) {
#pragma unroll
        for (int i = 0; i < 8; i++) {
            int idx = tid + i * 256;
            int r = idx >> 4, c4 = (idx & 15) * 4;
            int gr = bm + r;
            int ab = (r * 128 + c4 * 2) ^ ((r & 7) << 4);
            if (ASPLIT) {
                float4 v = make_float4(0.f, 0.f, 0.f, 0.f);
                if (gr < M) v = *(const float4*)(Af + abase + (size_t)gr * lda + k0 + c4);
                ushort h0, h1, h2, h3, l0, l1, l2, l3;
                split2(v.x, h0, l0); split2(v.y, h1, l1);
                split2(v.z, h2, l2); split2(v.w, h3, l3);
                *(ushort4*)((char*)Ah + ab) = make_ushort4(h0, h1, h2, h3);
                *(ushort4*)((char*)Al + ab) = make_ushort4(l0, l1, l2, l3);
            } else {
                ushort4 v = make_ushort4(0, 0, 0, 0);
                if (gr < M) v = *(const ushort4*)(Au + abase + (size_t)gr * lda + k0 + c4);
                *(ushort4*)((char*)Ah + ab) = v;
            }
        }
        if (!BT) {
#pragma unroll
            for (int i = 0; i < BN / 16; i++) {
                int idx = tid + i * 256;
                int kk = idx / (BN / 4);
                int c4 = (idx % (BN / 4)) * 4;
                float4 v = *(const float4*)(B + (size_t)(k0 + kk) * ldb + bcb + c4);
                float vv[4] = {v.x, v.y, v.z, v.w};
#pragma unroll
                for (int q = 0; q < 4; q++) {
                    int nl = c4 + q;
                    int bb = (nl * 128 + kk * 2) ^ ((nl & 7) << 4);
                    ushort h, l;
                    split2(vv[q], h, l);
                    *(ushort*)((char*)Bh + bb) = h;
                    *(ushort*)((char*)Bl + bb) = l;
                }
            }
        } else {
#pragma unroll
            for (int i = 0; i < BN / 16; i++) {
                int idx = tid + i * 256;
                int nl = idx >> 4, k4 = (idx & 15) * 4;
                float4 v = *(const float4*)(B + (size_t)(ny + nl) * ldb + k0 + k4);
                ushort h0, h1, h2, h3, l0, l1, l2, l3;
                split2(v.x, h0, l0); split2(v.y, h1, l1);
                split2(v.z, h2, l2); split2(v.w, h3, l3);
                int bb = (nl * 128 + k4 * 2) ^ ((nl & 7) << 4);
                *(ushort4*)((char*)Bh + bb) = make_ushort4(h0, h1, h2, h3);
                *(ushort4*)((char*)Bl + bb) = make_ushort4(l0, l1, l2, l3);
            }
        }
        __syncthreads();
#pragma unroll
        for (int ks = 0; ks < 2; ks++) {
            int kb = ks * 64 + (ln >> 4) * 16;
            bf16x8 ah[4], alo[ASPLIT ? 4 : 1], bh[NF], bl[NF];
#pragma unroll
            for (int mf = 0; mf < 4; mf++) {
                int r = wm * 64 + mf * 16 + (ln & 15);
                int ab = (r * 128 + kb) ^ ((r & 7) << 4);
                ah[mf] = *(bf16x8*)((char*)Ah + ab);
                if (ASPLIT) alo[mf] = *(bf16x8*)((char*)Al + ab);
            }
#pragma unroll
            for (int nf = 0; nf < NF; nf++) {
                int nl = wn * (BN / 2) + nf * 16 + (ln & 15);
                int bb = (nl * 128 + kb) ^ ((nl & 7) << 4);
                bh[nf] = *(bf16x8*)((char*)Bh + bb);
                bl[nf] = *(bf16x8*)((char*)Bl + bb);
            }
#pragma unroll
            for (int mf = 0; mf < 4; mf++)
#pragma unroll
                for (int nf = 0; nf < NF; nf++) {
                    acc[mf][nf] = __builtin_amdgcn_mfma_f32_16x16x32_bf16(ah[mf], bh[nf], acc[mf][nf], 0, 0, 0);
                    acc[mf][nf] = __builtin_amdgcn_mfma_f32_16x16x32_bf16(ah[mf], bl[nf], acc[mf][nf], 0, 0, 0);
                    if (ASPLIT)
                        acc[mf][nf] = __builtin_amdgcn_mfma_f32_16x16x32_bf16(alo[mf], bh[nf], acc[mf][nf], 0, 0, 0);
                }
        }
        __syncthreads();
    }
    float* Cf = (float*)Cptr;
    ushort* Cu = (ushort*)Cptr;
#pragma unroll
    for (int mf = 0; mf < 4; mf++)
#pragma unroll
        for (int nf = 0; nf < NF; nf++) {
            int colL = ny + wn * (BN / 2) + nf * 16 + (ln & 15);
#pragma unroll
            for (int j = 0; j < 4; j++) {
                int row = bm + wm * 64 + mf * 16 + (ln >> 4) * 4 + j;
                if (row < M) {
                    float v = acc[mf][nf][j];
                    if (ACT) {
                        v += bias[z * zC + colL];
                        v = v > 0.f ? v : (__expf(v) - 1.f);
                    }
                    size_t ci = (size_t)row * ldc + z * zC + colL;
                    if (OUTBF) Cu[ci] = f2bf_rne(v);
                    else       Cf[ci] = v;
                }
            }
        }
}

// ---------------- GRU (h0=0) + heads + SIR physics ----------------
__launch_bounds__(128)
__global__ void gru_heads_kernel(const float* __restrict__ gi, const float* __restrict__ b_ih,
                                 const float* __restrict__ b_hh, const float* __restrict__ cI,
                                 const float* __restrict__ cR, const float* __restrict__ Npop,
                                 const float* __restrict__ I0, const float* __restrict__ R0,
                                 const float* __restrict__ W_I, const float* __restrict__ b_I,
                                 const float* __restrict__ W_R, const float* __restrict__ b_R,
                                 const float* __restrict__ W_sir, const float* __restrict__ b_sir,
                                 float* __restrict__ out_predI, float* __restrict__ out_predR,
                                 float* __restrict__ out_phyI, float* __restrict__ out_phyR,
                                 float* __restrict__ out_h) {
    int n = blockIdx.x, t = threadIdx.x;
    __shared__ float hc[130];
    __shared__ float s_pr[2];
    const float* g = gi + (size_t)n * 384;
    float ir = g[t] + b_ih[t];
    float iz = g[128 + t] + b_ih[128 + t];
    float ih = g[256 + t] + b_ih[256 + t];
    float r = 1.f / (1.f + expf(-(ir + b_hh[t])));
    float z = 1.f / (1.f + expf(-(iz + b_hh[128 + t])));
    float nn = tanhf(ih + r * b_hh[256 + t]);
    float hv = (1.f - z) * nn;
    out_h[(size_t)n * 128 + t] = hv;
    hc[t] = hv;
    if (t == 0) { hc[128] = cI[n]; hc[129] = cR[n]; }
    __syncthreads();
    if (t < 32) {
        const float* Wr;
        float bb;
        int p;
        if (t < 15)      { p = t;      Wr = W_I + p * 130;   bb = b_I[p]; }
        else if (t < 30) { p = t - 15; Wr = W_R + p * 130;   bb = b_R[p]; }
        else             { p = t - 30; Wr = W_sir + p * 130; bb = b_sir[p]; }
        float s = bb;
        for (int d = 0; d < 130; d++) s += hc[d] * Wr[d];
        if (t < 15)      out_predI[(size_t)n * 15 + p] = s;
        else if (t < 30) out_predR[(size_t)n * 15 + p] = s;
        else             s_pr[p] = s;
    }
    __syncthreads();
    if (t == 0) {
        float alpha = 1.f / (1.f + expf(-s_pr[0]));
        float beta  = 1.f / (1.f + expf(-s_pr[1]));
        float Nv = Npop[n];
        float Iv = I0[n], Rv = R0[n];
        float S = Nv - Iv - Rv;
        float SoN = S / Nv;
        for (int st = 0; st < 15; st++) {
            float dIv = alpha * Iv * SoN - beta * Iv;
            float dRv = beta * Iv;
            out_phyI[(size_t)n * 15 + st] = dIv;
            out_phyR[(size_t)n * 15 + st] = dRv;
            Iv += dIv; Rv += dRv;
        }
    }
}

extern "C" void kernel_launch(void* const* d_in, const int* in_sizes, int n_in,
                              void* d_out, int out_size, void* d_ws, size_t ws_size,
                              hipStream_t stream) {
    const float* dynamic = (const float*)d_in[0];
    const int*   ei      = (const int*)d_in[1];
    const float* cI      = (const float*)d_in[2];
    const float* cR      = (const float*)d_in[3];
    const float* Npop    = (const float*)d_in[4];
    const float* I0      = (const float*)d_in[5];
    const float* R0      = (const float*)d_in[6];
    const float* W1      = (const float*)d_in[9];
    const float* a_src1  = (const float*)d_in[10];
    const float* a_dst1  = (const float*)d_in[11];
    const float* b1      = (const float*)d_in[12];
    const float* W2      = (const float*)d_in[13];
    const float* a_src2  = (const float*)d_in[14];
    const float* a_dst2  = (const float*)d_in[15];
    const float* b2      = (const float*)d_in[16];
    const float* W_ih    = (const float*)d_in[17];
    const float* b_ih    = (const float*)d_in[19];
    const float* b_hh    = (const float*)d_in[20];
    const float* W_I     = (const float*)d_in[21];
    const float* b_I     = (const float*)d_in[22];
    const float* W_R     = (const float*)d_in[23];
    const float* b_R     = (const float*)d_in[24];
    const float* W_sir   = (const float*)d_in[25];
    const float* b_sir   = (const float*)d_in[26];
    float* out = (float*)d_out;

    // ---- workspace layout (~60 MB) ----
    int* wsi = (int*)d_ws;
    int* offs    = wsi;              // 20001 (pad 20096)
    int* cursor  = wsi + 20096;      // 20000 (pad 20096)
    int* csr_src = wsi + 40192;      // 660000 (pad 660096)
    float* fp = (float*)(wsi + 700288);
    float* w1f = fp; fp += 1152;     // 128*8
    float* w2f = fp; fp += 640;      // 256*2
    float* al1 = fp; fp += 80128;    // 20000*4
    float* ar1 = fp; fp += 80128;
    float* al2 = fp; fp += 20096;
    float* ar2 = fp; fp += 20096;
    ushort* dyn_bf = (ushort*)fp; fp += 1280000;   // 20000*128 bf16
    float* x1 = fp; fp += 5120000;                 // [20000][256] f32; later x2 [20000][128]
    float* R  = fp; fp += 7680000;                 // agg_bf / xl2_bf / gi
    ushort* agg_bf = (ushort*)R;                   // [20000][512] bf16
    ushort* xl2_bf = (ushort*)R;                   // [20000][128] bf16 (after agg dead)
    float* gi = R;                                 // [20000][384] f32 (after xl2 dead)
    float* x2 = x1;                                // [20000][128] f32 (after x1 dead)

    hipMemsetAsync(cursor, 0, NN * sizeof(int), stream);
    // pre1: count_deg (2579 blocks) + fold_w1 + fold_w2
    pre1_kernel<<<2581, 256, 0, stream>>>(ei, cursor, W1, a_src1, a_dst1, w1f,
                                          W2, a_src2, a_dst2, w2f);
    scan_kernel<<<1, 1024, 0, stream>>>(cursor, offs);
    // pre2: fill_csr (2579 blocks) + alar_cast (5000 blocks)
    pre2_kernel<<<7579, 256, 0, stream>>>(ei, cursor, csr_src, dynamic, w1f, dyn_bf, al1, ar1);

    // GAT layer 1
    gat_gather_w<4, false><<<2500, 256, 0, stream>>>(dyn_bf, al1, ar1, offs, csr_src, nullptr, agg_bf);
    gemm3t<0, false, 1, false, 64><<<dim3(157, 1, 4), 256, 0, stream>>>(
        agg_bf, W1, b1, x1, NN, 128, 512, 256, 256, 128, 64, 64);

    // GAT layer 2
    alar_apply2<<<5000, 256, 0, stream>>>(x1, w2f, al2, ar2);
    gemm3t<1, false, 0, true, 128><<<dim3(157, 1, 1), 256, 0, stream>>>(
        x1, W2, nullptr, xl2_bf, NN, 256, 256, 128, 128, 0, 0, 0);
    gat_gather_w<1, true><<<2500, 256, 0, stream>>>(xl2_bf, al2, ar2, offs, csr_src, b2, x2);

    // gi = x2 @ W_ih^T
    gemm3t<1, true, 0, false, 128><<<dim3(157, 3, 1), 256, 0, stream>>>(
        x2, W_ih, nullptr, gi, NN, 128, 128, 128, 384, 0, 0, 0);

    // GRU + prediction heads + SIR
    gru_heads_kernel<<<NN, 128, 0, stream>>>(gi, b_ih, b_hh, cI, cR, Npop, I0, R0,
                                             W_I, b_I, W_R, b_R, W_sir, b_sir,
                                             out, out + 300000, out + 600000,
                                             out + 900000, out + 1200000);
}